// Round 1
// 898.648 us; speedup vs baseline: 1.2976x; 1.2976x over previous
//
#include <hip/hip_runtime.h>

#define DD 128
#define KSPLIT 8
#define BM 64
#define BK 64
#define K3R 32

typedef float f4 __attribute__((ext_vector_type(4)));
typedef _Float16 h4 __attribute__((ext_vector_type(4)));
typedef _Float16 h8 __attribute__((ext_vector_type(8)));
typedef unsigned int u32x4 __attribute__((ext_vector_type(4)));

// ---------------- K1: LayerNorm + gumbel gate + compaction (unchanged) ----------------
__global__ __launch_bounds__(256) void k1_ln_gate(
    const float* __restrict__ x, const float* __restrict__ u,
    const float* __restrict__ Wn, const float* __restrict__ bn,
    const float* __restrict__ g_in, const float* __restrict__ b_in,
    float* __restrict__ x_norm, float* __restrict__ gatef,
    int* __restrict__ rows_sel, int* __restrict__ cnt, int N) {
  int wave = threadIdx.x >> 6, lane = threadIdx.x & 63;
  int row = blockIdx.x * 4 + wave;
  if (row >= N) return;
  int d0 = lane, d1 = lane + 64;
  float x0 = x[(size_t)row * DD + d0];
  float x1 = x[(size_t)row * DD + d1];
  float s = x0 + x1;
#pragma unroll
  for (int off = 32; off; off >>= 1) s += __shfl_xor(s, off, 64);
  float mean = s * (1.0f / 128.0f);
  float dx0 = x0 - mean, dx1 = x1 - mean;
  float v = dx0 * dx0 + dx1 * dx1;
#pragma unroll
  for (int off = 32; off; off >>= 1) v += __shfl_xor(v, off, 64);
  float inv = 1.0f / sqrtf(v * (1.0f / 128.0f) + 1e-5f);
  float xn0 = dx0 * inv * g_in[d0] + b_in[d0];
  float xn1 = dx1 * inv * g_in[d1] + b_in[d1];
  x_norm[(size_t)row * DD + d0] = xn0;
  x_norm[(size_t)row * DD + d1] = xn1;
  float l0 = xn0 * Wn[2 * d0] + xn1 * Wn[2 * d1];
  float l1 = xn0 * Wn[2 * d0 + 1] + xn1 * Wn[2 * d1 + 1];
#pragma unroll
  for (int off = 32; off; off >>= 1) {
    l0 += __shfl_xor(l0, off, 64);
    l1 += __shfl_xor(l1, off, 64);
  }
  float u0 = u[2 * row], u1 = u[2 * row + 1];
  float g0 = -logf(-logf(fminf(fmaxf(u0, 1e-10f), 1.0f)) + 1e-10f);
  float g1 = -logf(-logf(fminf(fmaxf(u1, 1e-10f), 1.0f)) + 1e-10f);
  float z0 = l0 + bn[0] + g0;
  float z1 = l1 + bn[1] + g1;
  bool gate = (z1 > z0);
  if (lane == 0) {
    gatef[row] = gate ? 1.0f : 0.0f;
    if (gate) {
      int p = atomicAdd(cnt, 1);
      rows_sel[p] = row;
    }
  }
}

// ---------------- K1b: xg16T[d][n] = gate[n]*x_norm[n][d] in f16 (tiled transpose) ----
__global__ __launch_bounds__(256) void k1b_transpose(
    const float* __restrict__ x_norm, const float* __restrict__ gatef,
    _Float16* __restrict__ xg16T, int N) {
  __shared__ float tile[64][65];
  const int n0 = blockIdx.x * 64;
  const int d0 = blockIdx.y * 64;
  const int t = threadIdx.x;
  {
    const int c4 = (t & 15) * 4, r0 = t >> 4;
#pragma unroll
    for (int uu = 0; uu < 4; ++uu) {
      int r = r0 + 16 * uu;
      float gv = gatef[n0 + r];
      f4 v = *(const f4*)(x_norm + (size_t)(n0 + r) * DD + d0 + c4);
#pragma unroll
      for (int j = 0; j < 4; ++j) tile[r][c4 + j] = v[j] * gv;
    }
  }
  __syncthreads();
  {
    const int nq = t & 15, dr0 = t >> 4;
#pragma unroll
    for (int uu = 0; uu < 4; ++uu) {
      int d = dr0 + 16 * uu;
      h4 o;
#pragma unroll
      for (int j = 0; j < 4; ++j) o[j] = (_Float16)tile[nq * 4 + j][d];
      *(h4*)(xg16T + (size_t)(d0 + d) * N + n0 + nq * 4) = o;
    }
  }
}

// ---------------- K2: view2 = adj_sel @ xg via f16 MFMA, split-K atomics ----------------
// A tile: [BM][BK] f16 (128B rows), B tile: [DD][BK] f16; both 16B-XOR swizzled.
__global__ __launch_bounds__(256) void k2_mfma(
    const float* __restrict__ adj, const _Float16* __restrict__ xg16T,
    const int* __restrict__ rows_sel, const int* __restrict__ cnt,
    float* __restrict__ view2, int N) {
  __shared__ __align__(16) unsigned short Ab[BM * BK];
  __shared__ __align__(16) unsigned short Bb[DD * BK];
  __shared__ int rloc[BM];
  const int Nc = *cnt;
  const int rbase = blockIdx.x * BM;
  if (rbase >= Nc) return;
  const int t = threadIdx.x;
  if (t < BM) {
    int m = rbase + t;
    rloc[t] = rows_sel[m < Nc ? m : Nc - 1];
  }
  __syncthreads();
  const int lane = t & 63, wave = t >> 6;
  const int li = lane & 15, g = lane >> 4;
  // A staging mapping: thread covers row am, 4 f4-quads
  const int am = t >> 2, asub = t & 3;
  const size_t arow = (size_t)rloc[am] * (size_t)N;
  const int aswz = (am & 7) << 4;
  // B staging mapping: thread covers row bd, one 64B half
  const int bd = t >> 1, bhalf = t & 1;
  const size_t brow = (size_t)bd * (size_t)N;
  const int bswz = (bd & 7) << 4;
  // fragment-read constants
  const int arbyte = (wave * 16 + li) * (BK * 2);
  const int fswz = (li & 7) << 4;  // same for A rows (wave*16+li) and B rows (c*16+li)

  f4 acc[8];
#pragma unroll
  for (int i = 0; i < 8; ++i) acc[i] = (f4){0.f, 0.f, 0.f, 0.f};

  const int kchunk = N / KSPLIT;
  const int kbeg = blockIdx.y * kchunk;

  for (int kt = 0; kt < kchunk; kt += BK) {
    const int k0 = kbeg + kt;
    __syncthreads();  // previous tile's reads done
    // ---- stage A: gathered adj rows, fp32 -> f16
#pragma unroll
    for (int i = 0; i < 4; ++i) {
      int q = asub + 4 * i;  // f4-quad 0..15 within 64-float row chunk
      f4 v = *(const f4*)(adj + arow + (size_t)(k0 + q * 4));
      h4 hv;
      hv[0] = (_Float16)v[0];
      hv[1] = (_Float16)v[1];
      hv[2] = (_Float16)v[2];
      hv[3] = (_Float16)v[3];
      *(h4*)((char*)Ab + am * (BK * 2) + ((q * 8) ^ aswz)) = hv;
    }
    // ---- stage B: xg16T rows (already f16), straight 16B copies
#pragma unroll
    for (int i = 0; i < 4; ++i) {
      int boff = bhalf * 64 + i * 16;  // byte offset within 128B row
      u32x4 v = *(const u32x4*)((const char*)xg16T + (brow + (size_t)k0) * 2 + boff);
      *(u32x4*)((char*)Bb + bd * (BK * 2) + (boff ^ bswz)) = v;
    }
    __syncthreads();
    // ---- compute: 2 k-steps of 16x16x32, 8 col-tiles each
#pragma unroll
    for (int s = 0; s < 2; ++s) {
      h8 af = *(const h8*)((const char*)Ab + arbyte + ((s * 64 + g * 16) ^ fswz));
#pragma unroll
      for (int c = 0; c < 8; ++c) {
        int br = c * 16 + li;
        h8 bf = *(const h8*)((const char*)Bb + br * (BK * 2) +
                             ((s * 64 + g * 16) ^ fswz));
        acc[c] = __builtin_amdgcn_mfma_f32_16x16x32_f16(af, bf, acc[c], 0, 0, 0);
      }
    }
  }
  // ---- epilogue: split-K combine via atomics (C/D layout: col=li, row=g*4+r)
#pragma unroll
  for (int c = 0; c < 8; ++c) {
#pragma unroll
    for (int r = 0; r < 4; ++r) {
      int mi = wave * 16 + g * 4 + r;
      if (rbase + mi < Nc)
        atomicAdd(view2 + (size_t)rloc[mi] * DD + c * 16 + li, acc[c][r]);
    }
  }
}

// ---------------- K3: fusion gate + mix + residual LN; 32 rows/block, 4 rows/thread ----
__global__ __launch_bounds__(256) void k3_epilogue(
    const float* __restrict__ x, const float* __restrict__ x_norm,
    const float* __restrict__ view2,
    const float* __restrict__ W1, const float* __restrict__ b1,
    const float* __restrict__ W2, const float* __restrict__ b2,
    const float* __restrict__ Wg, const float* __restrict__ bg,
    const float* __restrict__ g_out, const float* __restrict__ b_out,
    float* __restrict__ out, int N) {
  __shared__ float t1[K3R][DD];
  __shared__ float t2[K3R][DD];
  const int row0 = blockIdx.x * K3R;
  const int t = threadIdx.x;
  {
    const int cs = (t & 31) * 4, rs = t >> 5;
#pragma unroll
    for (int uu = 0; uu < 4; ++uu) {
      int r = rs + 8 * uu;
      *(f4*)&t1[r][cs] = *(const f4*)(x_norm + (size_t)(row0 + r) * DD + cs);
      *(f4*)&t2[r][cs] = *(const f4*)(view2 + (size_t)(row0 + r) * DD + cs);
    }
  }
  __syncthreads();
  const int rg = t >> 5;          // row group: rows rg*4 .. rg*4+3
  const int cb = (t & 31) * 4;    // 4 output columns
  f4 zero = {0.f, 0.f, 0.f, 0.f};
  f4 fg4[4] = {zero, zero, zero, zero};
  f4 h14[4] = {zero, zero, zero, zero};
  f4 h24[4] = {zero, zero, zero, zero};
#pragma unroll 2
  for (int j = 0; j < DD; ++j) {
    f4 wg1 = *(const f4*)(Wg + j * DD + cb);
    f4 wg2 = *(const f4*)(Wg + (j + DD) * DD + cb);
    f4 w1 = *(const f4*)(W1 + j * DD + cb);
    f4 w2 = *(const f4*)(W2 + j * DD + cb);
#pragma unroll
    for (int rr = 0; rr < 4; ++rr) {
      float tv1 = t1[rg * 4 + rr][j];
      float tv2 = t2[rg * 4 + rr][j];
      fg4[rr] += tv1 * wg1 + tv2 * wg2;
      h14[rr] += tv1 * w1;
      h24[rr] += tv2 * w2;
    }
  }
  f4 bgv = *(const f4*)(bg + cb);
  f4 b1v = *(const f4*)(b1 + cb);
  f4 b2v = *(const f4*)(b2 + cb);
  f4 goutv = *(const f4*)(g_out + cb);
  f4 boutv = *(const f4*)(b_out + cb);
#pragma unroll
  for (int rr = 0; rr < 4; ++rr) {
    int row = row0 + rg * 4 + rr;
    f4 fg;
#pragma unroll
    for (int c = 0; c < 4; ++c)
      fg[c] = 1.0f / (1.0f + expf(-(fg4[rr][c] + bgv[c])));
    f4 h1 = h14[rr] + b1v;
    f4 h2 = h24[rr] + b2v;
    f4 fused = fg * h1 + (1.0f - fg) * h2;
    f4 xres = *(const f4*)(x + (size_t)row * DD + cb);
    f4 sres = fused + xres;
    float ps = sres[0] + sres[1] + sres[2] + sres[3];
#pragma unroll
    for (int off = 16; off; off >>= 1) ps += __shfl_xor(ps, off, 32);
    float mean = ps * (1.0f / 128.0f);
    f4 dx = sres - mean;
    float pq = dx[0] * dx[0] + dx[1] * dx[1] + dx[2] * dx[2] + dx[3] * dx[3];
#pragma unroll
    for (int off = 16; off; off >>= 1) pq += __shfl_xor(pq, off, 32);
    float inv = 1.0f / sqrtf(pq * (1.0f / 128.0f) + 1e-5f);
    f4 o = dx * inv * goutv + boutv;
    *(f4*)(out + (size_t)row * DD + cb) = o;
  }
}

extern "C" void kernel_launch(void* const* d_in, const int* in_sizes, int n_in,
                              void* d_out, int out_size, void* d_ws, size_t ws_size,
                              hipStream_t stream) {
  const float* x = (const float*)d_in[0];
  const float* adj = (const float*)d_in[1];
  const float* u = (const float*)d_in[2];
  const float* W1 = (const float*)d_in[3];
  const float* b1 = (const float*)d_in[4];
  const float* W2 = (const float*)d_in[5];
  const float* b2 = (const float*)d_in[6];
  const float* Wg = (const float*)d_in[7];
  const float* bg = (const float*)d_in[8];
  const float* Wn = (const float*)d_in[9];
  const float* bn = (const float*)d_in[10];
  const float* g_in = (const float*)d_in[11];
  const float* b_in = (const float*)d_in[12];
  const float* g_out = (const float*)d_in[13];
  const float* b_out = (const float*)d_in[14];
  float* out = (float*)d_out;

  const int N = in_sizes[2] / 2;  // 12288

  char* ws = (char*)d_ws;
  int* cnt = (int*)ws;                             // 4 B (pad to 256)
  int* rows_sel = (int*)(ws + 256);                // N*4
  size_t o_gate = 256 + (size_t)N * 4;
  float* gatef = (float*)(ws + o_gate);            // N*4
  size_t o_xn = o_gate + (size_t)N * 4;
  float* x_norm = (float*)(ws + o_xn);             // N*128*4
  size_t o_v2 = o_xn + (size_t)N * DD * 4;
  float* view2 = (float*)(ws + o_v2);              // N*128*4
  size_t o_xt = o_v2 + (size_t)N * DD * 4;
  _Float16* xg16T = (_Float16*)(ws + o_xt);        // 128*N*2  (~15.8 MB total)

  hipMemsetAsync(cnt, 0, 4, stream);
  hipMemsetAsync(view2, 0, (size_t)N * DD * 4, stream);

  k1_ln_gate<<<N / 4, 256, 0, stream>>>(x, u, Wn, bn, g_in, b_in, x_norm, gatef,
                                        rows_sel, cnt, N);
  k1b_transpose<<<dim3(N / 64, DD / 64), 256, 0, stream>>>(x_norm, gatef, xg16T, N);
  k2_mfma<<<dim3(N / BM, KSPLIT), 256, 0, stream>>>(adj, xg16T, rows_sel, cnt,
                                                    view2, N);
  k3_epilogue<<<N / K3R, 256, 0, stream>>>(x, x_norm, view2, W1, b1, W2, b2, Wg,
                                           bg, g_out, b_out, out, N);
}